// Round 2
// baseline (1236.424 us; speedup 1.0000x reference)
//
#include <hip/hip_runtime.h>
#include <cstdint>
#include <cstddef>

#define B_   32
#define LQ   2048
#define LK   2048
#define DK   64
#define DV   64
#define TQ   32
#define LDP  2056   // padded P row length in bf16 elems; byte stride 4112 = 257*16 (16B-aligned, 2-way-max LDS conflicts)

typedef short bf16x8 __attribute__((ext_vector_type(8)));
typedef float f32x4  __attribute__((ext_vector_type(4)));

// exp(x/8) = exp2(x * log2(e)/8)
#define KSCALE 0.1803368801111204f

__device__ __forceinline__ short f2bf(float f) {          // round-to-nearest-even fp32->bf16
  unsigned u = __builtin_bit_cast(unsigned, f);
  u += 0x7fffu + ((u >> 16) & 1u);
  return (short)(u >> 16);
}
__device__ __forceinline__ float bflo(unsigned u) { return __builtin_bit_cast(float, u << 16); }
__device__ __forceinline__ float bfhi(unsigned u) { return __builtin_bit_cast(float, u & 0xffff0000u); }

__device__ __forceinline__ bf16x8 pack8(float4 a, float4 b) {
  bf16x8 r;
  r[0]=f2bf(a.x); r[1]=f2bf(a.y); r[2]=f2bf(a.z); r[3]=f2bf(a.w);
  r[4]=f2bf(b.x); r[5]=f2bf(b.y); r[6]=f2bf(b.z); r[7]=f2bf(b.w);
  return r;
}

__global__ __launch_bounds__(512, 2) void sdpa_kernel(
    const float* __restrict__ q, const float* __restrict__ k,
    const float* __restrict__ v, const int* __restrict__ mask,
    float* __restrict__ out, float* __restrict__ attn) {
  __shared__ short P[TQ][LDP];     // unnormalized exp(S), bf16
  __shared__ float rowsum[TQ];
  __shared__ float rinv[TQ];

  const int tid  = threadIdx.x;
  const int wave = tid >> 6;       // 0..7
  const int lane = tid & 63;
  const int quad = lane >> 4;      // 0..3
  const int l15  = lane & 15;
  const int b     = blockIdx.y;
  const int qbase = blockIdx.x * TQ;

  if (tid < TQ) rowsum[tid] = 0.0f;
  __syncthreads();

  // ---- Q fragments: A[m=l15][k=quad*8+j], two m-tiles x two k-halves ----
  const float* qr  = q + ((size_t)b * LQ + qbase + l15) * DK + quad * 8;
  const float* qr1 = qr + 16 * DK;
  bf16x8 qa00 = pack8(*(const float4*)(qr),       *(const float4*)(qr  + 4));
  bf16x8 qa01 = pack8(*(const float4*)(qr  + 32), *(const float4*)(qr  + 36));
  bf16x8 qa10 = pack8(*(const float4*)(qr1),      *(const float4*)(qr1 + 4));
  bf16x8 qa11 = pack8(*(const float4*)(qr1 + 32), *(const float4*)(qr1 + 36));

  // ---- Phase 1: S = Q K^T, p = mask ? 0 : exp(S/temp), bf16 -> LDS, row sums ----
  // wave handles n-tiles nt = wave, wave+8, ... (16 of 128)
  const float* kbase = k + (size_t)b * LK * DK + (size_t)l15 * DK + quad * 8;
  const int*   mbase = mask + (size_t)b * LQ * LK + (size_t)(qbase + quad * 4) * LK + l15;
  const f32x4 z4 = {0.f, 0.f, 0.f, 0.f};

  float4 kp0, kp1, kp2, kp3;
  int mp[8];
  int nt = wave;
  {
    const float* kr = kbase + (size_t)nt * (16 * DK);
    kp0 = *(const float4*)(kr);      kp1 = *(const float4*)(kr + 4);
    kp2 = *(const float4*)(kr + 32); kp3 = *(const float4*)(kr + 36);
    const int* mr = mbase + nt * 16;
    #pragma unroll
    for (int r = 0; r < 4; ++r) {
      mp[r]     = __builtin_nontemporal_load(mr + (size_t)r * LK);
      mp[4 + r] = __builtin_nontemporal_load(mr + (size_t)(16 + r) * LK);
    }
  }
  float sum0[4] = {0,0,0,0}, sum1[4] = {0,0,0,0};
  #pragma unroll 1
  for (int i = 0; i < 16; ++i) {
    float4 kc0 = kp0, kc1 = kp1, kc2 = kp2, kc3 = kp3;
    int mc[8];
    #pragma unroll
    for (int r = 0; r < 8; ++r) mc[r] = mp[r];
    const int ntc = nt;
    nt += 8;
    if (i != 15) {   // software prefetch next tile (uniform branch)
      const float* kr = kbase + (size_t)nt * (16 * DK);
      kp0 = *(const float4*)(kr);      kp1 = *(const float4*)(kr + 4);
      kp2 = *(const float4*)(kr + 32); kp3 = *(const float4*)(kr + 36);
      const int* mr = mbase + nt * 16;
      #pragma unroll
      for (int r = 0; r < 4; ++r) {
        mp[r]     = __builtin_nontemporal_load(mr + (size_t)r * LK);
        mp[4 + r] = __builtin_nontemporal_load(mr + (size_t)(16 + r) * LK);
      }
    }
    bf16x8 kb0 = pack8(kc0, kc1);   // B[k][n]=K[n][k]: n=l15, k=quad*8+j
    bf16x8 kb1 = pack8(kc2, kc3);
    f32x4 acc0 = __builtin_amdgcn_mfma_f32_16x16x32_bf16(qa00, kb0, z4, 0, 0, 0);
    acc0       = __builtin_amdgcn_mfma_f32_16x16x32_bf16(qa01, kb1, acc0, 0, 0, 0);
    f32x4 acc1 = __builtin_amdgcn_mfma_f32_16x16x32_bf16(qa10, kb0, z4, 0, 0, 0);
    acc1       = __builtin_amdgcn_mfma_f32_16x16x32_bf16(qa11, kb1, acc1, 0, 0, 0);
    // D[row=quad*4+r][col=l15]
    const int col = ntc * 16 + l15;
    #pragma unroll
    for (int r = 0; r < 4; ++r) {
      float p0 = mc[r]     ? 0.0f : __builtin_amdgcn_exp2f(acc0[r] * KSCALE);
      float p1 = mc[4 + r] ? 0.0f : __builtin_amdgcn_exp2f(acc1[r] * KSCALE);
      P[quad * 4 + r][col]      = f2bf(p0);
      P[16 + quad * 4 + r][col] = f2bf(p1);
      sum0[r] += p0;
      sum1[r] += p1;
    }
  }
  // quad-level (16-lane) reduction: each quad owns rows quad*4+r
  #pragma unroll
  for (int r = 0; r < 4; ++r) {
    float s0 = sum0[r], s1 = sum1[r];
    #pragma unroll
    for (int off = 1; off < 16; off <<= 1) {
      s0 += __shfl_xor(s0, off);
      s1 += __shfl_xor(s1, off);
    }
    if (l15 == 0) {
      atomicAdd(&rowsum[quad * 4 + r], s0);
      atomicAdd(&rowsum[16 + quad * 4 + r], s1);
    }
  }
  __syncthreads();
  if (tid < TQ) rinv[tid] = 1.0f / rowsum[tid];
  __syncthreads();

  if (wave < 4) {
    // ---- Phase 2a (waves 0-3): O = P V, one 16-col V tile per wave, both m-tiles ----
    const float* vbase = v + (size_t)b * LK * DV + wave * 16 + l15;
    f32x4 o0 = z4, o1 = z4;
    float fv[8];
    #pragma unroll
    for (int j = 0; j < 8; ++j) fv[j] = vbase[(size_t)(quad * 8 + j) * DV];
    #pragma unroll 1
    for (int kt = 0; kt < 64; ++kt) {
      float fc[8];
      #pragma unroll
      for (int j = 0; j < 8; ++j) fc[j] = fv[j];
      if (kt != 63) {   // prefetch next B-frag (V is L2-resident)
        #pragma unroll
        for (int j = 0; j < 8; ++j)
          fv[j] = vbase[(size_t)((kt + 1) * 32 + quad * 8 + j) * DV];
      }
      bf16x8 bv;
      #pragma unroll
      for (int j = 0; j < 8; ++j) bv[j] = f2bf(fc[j]);
      bf16x8 a0 = *(const bf16x8*)&P[l15][kt * 32 + quad * 8];
      bf16x8 a1 = *(const bf16x8*)&P[16 + l15][kt * 32 + quad * 8];
      o0 = __builtin_amdgcn_mfma_f32_16x16x32_bf16(a0, bv, o0, 0, 0, 0);
      o1 = __builtin_amdgcn_mfma_f32_16x16x32_bf16(a1, bv, o1, 0, 0, 0);
    }
    #pragma unroll
    for (int r = 0; r < 4; ++r) {
      const int row0 = quad * 4 + r, row1 = 16 + row0;
      out[((size_t)b * LQ + qbase + row0) * DV + wave * 16 + l15] = o0[r] * rinv[row0];
      out[((size_t)b * LQ + qbase + row1) * DV + wave * 16 + l15] = o1[r] * rinv[row1];
    }
  } else {
    // ---- Phase 2b (waves 4-7): normalize + stream attn (nontemporal) ----
    const int ww = wave - 4;
    float* abase = attn + ((size_t)b * LQ + qbase) * (size_t)LK;
    #pragma unroll 1
    for (int j = 0; j < 8; ++j) {
      const int row = ww * 8 + j;
      const float ri = rinv[row];
      float* dst = abase + (size_t)row * LK;
      #pragma unroll
      for (int it = 0; it < 8; ++it) {
        const int c = it * 256 + lane * 4;
        uint2 u = *(const uint2*)&P[row][c];
        f32x4 val;
        val[0] = bflo(u.x) * ri;
        val[1] = bfhi(u.x) * ri;
        val[2] = bflo(u.y) * ri;
        val[3] = bfhi(u.y) * ri;
        __builtin_nontemporal_store(val, (f32x4*)(dst + c));
      }
    }
  }
}

extern "C" void kernel_launch(void* const* d_in, const int* in_sizes, int n_in,
                              void* d_out, int out_size, void* d_ws, size_t ws_size,
                              hipStream_t stream) {
  (void)in_sizes; (void)n_in; (void)out_size; (void)d_ws; (void)ws_size;
  const float* q    = (const float*)d_in[0];
  const float* k    = (const float*)d_in[1];
  const float* v    = (const float*)d_in[2];
  const int*   mask = (const int*)d_in[3];
  float* out  = (float*)d_out;
  float* attn = out + (size_t)B_ * LQ * DV;   // outputs concatenated: (out, attn)
  dim3 grid(LQ / TQ, B_);
  sdpa_kernel<<<grid, 512, 0, stream>>>(q, k, v, mask, out, attn);
}